// Round 8
// baseline (224.870 us; speedup 1.0000x reference)
//
#include <hip/hip_runtime.h>
#include <math.h>

typedef _Float16 half_t;
typedef _Float16 half8 __attribute__((ext_vector_type(8)));
typedef unsigned short ushort_t;

#define BATCH 4096
#define SEQL  512
#define NF    32
#define DEMB  8
#define DOUT  64

// windows: ks=2,3,4,5 -> 25,125,625,3125 rows; concat offsets 0,25,150,775
#define NWIN_TOTAL 3900
#define HWIN_OFF   4096   // float index into ws: fp16 h-table (3900*32 half = 249600 B)
#define TOFF       70000  // float index into ws: tap table T[14][5][32] = 2240 floats
#define DUMP1      (4*1024*1024)   // float index: V1 dump (4096*64 floats)
#define DUMP2      (8*1024*1024)   // float index: V2 dump

__device__ __forceinline__ float gelu_exact(float x) {
    return 0.5f * x * (1.0f + erff(x * 0.70710678118654752f));
}

// Stage A: tap table. T[tapg][d][f] = sum_c emb[d][c] * cw[f][c][t]
__global__ __launch_bounds__(256) void precompute_taps(
    const float* __restrict__ emb,
    const float* __restrict__ cw0, const float* __restrict__ cw1,
    const float* __restrict__ cw2, const float* __restrict__ cw3,
    float* __restrict__ ws)
{
    const int gid = blockIdx.x * blockDim.x + threadIdx.x;
    if (gid >= 14 * 5 * NF) return;
    const int f = gid & 31;
    const int r = gid >> 5;          // 0..69
    const int tapg = r / 5;
    const int d    = r % 5;

    int ks, t; const float* cw;
    if (tapg < 2)      { ks = 2; cw = cw0; t = tapg; }
    else if (tapg < 5) { ks = 3; cw = cw1; t = tapg - 2; }
    else if (tapg < 9) { ks = 4; cw = cw2; t = tapg - 5; }
    else               { ks = 5; cw = cw3; t = tapg - 9; }

    const float* e = emb + d * DEMB;
    float s = 0.0f;
#pragma unroll
    for (int c = 0; c < DEMB; ++c)
        s += e[c] * cw[(f * DEMB + c) * ks + t];
    ws[TOFF + r * NF + f] = s;
}

// Stage B: window table via tap table — coalesced reads only.
__global__ __launch_bounds__(256) void precompute_windows(
    const float* __restrict__ cb0, const float* __restrict__ aw0, const float* __restrict__ ab0,
    const float* __restrict__ cb1, const float* __restrict__ aw1, const float* __restrict__ ab1,
    const float* __restrict__ cb2, const float* __restrict__ aw2, const float* __restrict__ ab2,
    const float* __restrict__ cb3, const float* __restrict__ aw3, const float* __restrict__ ab3,
    float* __restrict__ ws)
{
    const int gid = blockIdx.x * blockDim.x + threadIdx.x;
    if (gid >= NWIN_TOTAL * NF) return;
    const int wgid = gid >> 5;
    const int f    = gid & 31;

    int w, ks, cum;
    const float *cb, *aw, *ab;
    if (wgid < 25)       { w = wgid;       ks = 2; cum = 0; cb = cb0; aw = aw0; ab = ab0; }
    else if (wgid < 150) { w = wgid - 25;  ks = 3; cum = 2; cb = cb1; aw = aw1; ab = ab1; }
    else if (wgid < 775) { w = wgid - 150; ks = 4; cum = 5; cb = cb2; aw = aw2; ab = ab2; }
    else                 { w = wgid - 775; ks = 5; cum = 9; cb = cb3; aw = aw3; ab = ab3; }

    float h = cb[f];
    int ww = w;
    for (int t = ks - 1; t >= 0; --t) {
        int d = ww % 5; ww /= 5;
        h += ws[TOFF + ((cum + t) * 5 + d) * NF + f];
    }
    float g = gelu_exact(h);
    ((half_t*)(ws + HWIN_OFF))[wgid * NF + f] = (half_t)g;   // fp16 table, row = 64 B

    float s = g * aw[f];
#pragma unroll
    for (int off = 16; off; off >>= 1) s += __shfl_xor(s, off, 32);
    if (f == 0) ws[wgid] = s + ab[0];        // fp32 score table
}

// V0 = full; V1 = no score-gather (arith score); V2 = no pass-2 scatter (row 0).
template<int V>
__global__ __launch_bounds__(256) void fused_main(
    const int*   __restrict__ xidx,
    const float* __restrict__ ws,
    const float* __restrict__ projw, const float* __restrict__ projb,
    const float* __restrict__ gamma, const float* __restrict__ beta,
    float* __restrict__ out)
{
    __shared__ int      xs[SEQL];
    __shared__ float    pwS[4][SEQL];
    __shared__ ushort_t pwid[4][SEQL];
    __shared__ float    feat[4 * NF];

    const int b   = blockIdx.x;
    const int tid = threadIdx.x;
    const half_t* hwin16 = (const half_t*)(ws + HWIN_OFF);

#pragma unroll
    for (int i = tid; i < SEQL / 4; i += 256)
        ((int4*)xs)[i] = ((const int4*)(xidx + b * SEQL))[i];
    __syncthreads();

    const int wave = tid >> 6;
    const int lane = tid & 63;

    constexpr int KS[4]  = {2, 3, 4, 5};
    constexpr int SWB[4] = {0, 25, 150, 775};

    const int ks = KS[wave];
    const int Lp = SEQL + 1 - ks;
    const float* swin = ws + SWB[wave];
    const half_t* tab = hwin16 + SWB[wave] * NF;

    // ---- pass 1 ----
    {
        float sv[8];
        float m = -INFINITY;
#pragma unroll
        for (int it = 0; it < 8; ++it) {
            int l = lane + it * 64;
            int w = 0; float s = -INFINITY;
            if (l < Lp) {
                w = xs[l];
                for (int t = 1; t < ks; ++t) w = w * 5 + xs[l + t];
                if constexpr (V == 1) s = (float)w * 0.001f;   // no score gather
                else                  s = swin[w];
            }
            pwid[wave][l] = (ushort_t)w;
            sv[it] = s;
            m = fmaxf(m, s);
        }
#pragma unroll
        for (int off = 32; off; off >>= 1) m = fmaxf(m, __shfl_xor(m, off));

        float ssum = 0.0f;
#pragma unroll
        for (int it = 0; it < 8; ++it) {
            sv[it] = __expf(sv[it] - m);
            ssum += sv[it];
        }
#pragma unroll
        for (int off = 32; off; off >>= 1) ssum += __shfl_xor(ssum, off);
        const float inv = 1.0f / ssum;
#pragma unroll
        for (int it = 0; it < 8; ++it)
            pwS[wave][lane + it * 64] = sv[it] * inv;
    }
    __syncthreads();

    // ---- pass 2 ----
    const int quad = lane & 3;
    const int pg   = lane >> 2;

    float a[8];
#pragma unroll
    for (int j = 0; j < 8; ++j) a[j] = 0.0f;

#pragma unroll 8
    for (int it = 0; it < 32; ++it) {
        const int pos = it * 16 + pg;
        const float p = pwS[wave][pos];
        int off = ((int)pwid[wave][pos]) << 6;
        if constexpr (V == 2) off = (((int)pwid[wave][pos]) >> 13) << 6;  // always 0; opaque to compiler
        half8 r = *(const half8*)((const char*)tab + off + quad * 16);
#pragma unroll
        for (int j = 0; j < 8; ++j)
            a[j] += p * (float)r[j];
    }

#pragma unroll
    for (int off = 4; off < 64; off <<= 1) {
#pragma unroll
        for (int j = 0; j < 8; ++j) a[j] += __shfl_xor(a[j], off);
    }
    if (lane < 4) {
        float* fp = feat + wave * NF + lane * 8;
#pragma unroll
        for (int j = 0; j < 8; ++j) fp[j] = a[j];
    }
    __syncthreads();

    // ---- projection + GELU + LayerNorm (wave 0) ----
    if (tid < DOUT) {
        float z = projb[tid];
        const float4* pwr = (const float4*)(projw + tid * (4 * NF));
#pragma unroll
        for (int q = 0; q < 32; ++q) {
            float4 wq = pwr[q];
            const float* fj = feat + q * 4;
            z += wq.x * fj[0] + wq.y * fj[1] + wq.z * fj[2] + wq.w * fj[3];
        }
        z = gelu_exact(z);

        float s1 = z, s2 = z * z;
#pragma unroll
        for (int off = 32; off; off >>= 1) {
            s1 += __shfl_xor(s1, off);
            s2 += __shfl_xor(s2, off);
        }
        const float mu  = s1 * (1.0f / 64.0f);
        const float var = s2 * (1.0f / 64.0f) - mu * mu;
        const float r   = rsqrtf(var + 1e-5f);
        out[b * DOUT + tid] = (z - mu) * r * gamma[tid] + beta[tid];
    }
}

extern "C" void kernel_launch(void* const* d_in, const int* in_sizes, int n_in,
                              void* d_out, int out_size, void* d_ws, size_t ws_size,
                              hipStream_t stream) {
    const int*   xidx = (const int*)d_in[0];
    const float* emb  = (const float*)d_in[1];
    const float* cw[4]; const float* cb[4]; const float* aw[4]; const float* ab[4];
    for (int i = 0; i < 4; ++i) {
        cw[i] = (const float*)d_in[2 + 4 * i];
        cb[i] = (const float*)d_in[3 + 4 * i];
        aw[i] = (const float*)d_in[4 + 4 * i];
        ab[i] = (const float*)d_in[5 + 4 * i];
    }
    const float* projw = (const float*)d_in[18];
    const float* projb = (const float*)d_in[19];
    const float* gm    = (const float*)d_in[20];
    const float* bt    = (const float*)d_in[21];
    float* ws  = (float*)d_ws;
    float* out = (float*)d_out;

    hipLaunchKernelGGL(precompute_taps, dim3((14 * 5 * NF + 255) / 256), dim3(256), 0, stream,
                       emb, cw[0], cw[1], cw[2], cw[3], ws);

    hipLaunchKernelGGL(precompute_windows, dim3((NWIN_TOTAL * NF + 255) / 256), dim3(256), 0, stream,
                       cb[0], aw[0], ab[0],
                       cb[1], aw[1], ab[1],
                       cb[2], aw[2], ab[2],
                       cb[3], aw[3], ab[3],
                       ws);

    // diagnostics first (write to ws dumps), full variant last (writes d_out)
    hipLaunchKernelGGL(fused_main<1>, dim3(BATCH), dim3(256), 0, stream,
                       xidx, ws, projw, projb, gm, bt, ws + DUMP1);
    hipLaunchKernelGGL(fused_main<2>, dim3(BATCH), dim3(256), 0, stream,
                       xidx, ws, projw, projb, gm, bt, ws + DUMP2);
    hipLaunchKernelGGL(fused_main<0>, dim3(BATCH), dim3(256), 0, stream,
                       xidx, ws, projw, projb, gm, bt, out);
}

// Round 9
// 144.726 us; speedup vs baseline: 1.5538x; 1.5538x over previous
//
#include <hip/hip_runtime.h>
#include <math.h>

typedef _Float16 half_t;
typedef _Float16 half8 __attribute__((ext_vector_type(8)));
typedef unsigned short ushort_t;

#define BATCH 4096
#define SEQL  512
#define NF    32
#define DEMB  8
#define DOUT  64

// windows: ks=2,3,4,5 -> 25,125,625,3125 rows; concat offsets 0,25,150,775
#define NWIN_TOTAL 3900
#define HWIN_OFF   4096   // float index into ws: fp16 h-table (3900*32 half = 249600 B)
#define TOFF       70000  // float index into ws: tap table T[14][5][32] = 2240 floats

__device__ __forceinline__ float gelu_exact(float x) {
    return 0.5f * x * (1.0f + erff(x * 0.70710678118654752f));
}

// Stage A: tap table. T[tapg][d][f] = sum_c emb[d][c] * cw[f][c][t]
__global__ __launch_bounds__(256) void precompute_taps(
    const float* __restrict__ emb,
    const float* __restrict__ cw0, const float* __restrict__ cw1,
    const float* __restrict__ cw2, const float* __restrict__ cw3,
    float* __restrict__ ws)
{
    const int gid = blockIdx.x * blockDim.x + threadIdx.x;
    if (gid >= 14 * 5 * NF) return;
    const int f = gid & 31;
    const int r = gid >> 5;          // 0..69
    const int tapg = r / 5;
    const int d    = r % 5;

    int ks, t; const float* cw;
    if (tapg < 2)      { ks = 2; cw = cw0; t = tapg; }
    else if (tapg < 5) { ks = 3; cw = cw1; t = tapg - 2; }
    else if (tapg < 9) { ks = 4; cw = cw2; t = tapg - 5; }
    else               { ks = 5; cw = cw3; t = tapg - 9; }

    const float* e = emb + d * DEMB;
    float s = 0.0f;
#pragma unroll
    for (int c = 0; c < DEMB; ++c)
        s += e[c] * cw[(f * DEMB + c) * ks + t];
    ws[TOFF + r * NF + f] = s;
}

// Stage B: window table via tap table — coalesced reads only.
__global__ __launch_bounds__(256) void precompute_windows(
    const float* __restrict__ cb0, const float* __restrict__ aw0, const float* __restrict__ ab0,
    const float* __restrict__ cb1, const float* __restrict__ aw1, const float* __restrict__ ab1,
    const float* __restrict__ cb2, const float* __restrict__ aw2, const float* __restrict__ ab2,
    const float* __restrict__ cb3, const float* __restrict__ aw3, const float* __restrict__ ab3,
    float* __restrict__ ws)
{
    const int gid = blockIdx.x * blockDim.x + threadIdx.x;
    if (gid >= NWIN_TOTAL * NF) return;
    const int wgid = gid >> 5;
    const int f    = gid & 31;

    int w, ks, cum;
    const float *cb, *aw, *ab;
    if (wgid < 25)       { w = wgid;       ks = 2; cum = 0; cb = cb0; aw = aw0; ab = ab0; }
    else if (wgid < 150) { w = wgid - 25;  ks = 3; cum = 2; cb = cb1; aw = aw1; ab = ab1; }
    else if (wgid < 775) { w = wgid - 150; ks = 4; cum = 5; cb = cb2; aw = aw2; ab = ab2; }
    else                 { w = wgid - 775; ks = 5; cum = 9; cb = cb3; aw = aw3; ab = ab3; }

    float h = cb[f];
    int ww = w;
    for (int t = ks - 1; t >= 0; --t) {
        int d = ww % 5; ww /= 5;
        h += ws[TOFF + ((cum + t) * 5 + d) * NF + f];
    }
    float g = gelu_exact(h);
    ((half_t*)(ws + HWIN_OFF))[wgid * NF + f] = (half_t)g;   // fp16 table, row = 64 B

    float s = g * aw[f];
#pragma unroll
    for (int off = 16; off; off >>= 1) s += __shfl_xor(s, off, 32);
    if (f == 0) ws[wgid] = s + ab[0];        // fp32 score table
}

__global__ __launch_bounds__(256) void fused_main(
    const int*   __restrict__ xidx,
    const float* __restrict__ ws,
    const float* __restrict__ projw, const float* __restrict__ projb,
    const float* __restrict__ gamma, const float* __restrict__ beta,
    float* __restrict__ out)
{
    __shared__ int      xs[SEQL];
    __shared__ float    pwS[4][SEQL];
    __shared__ ushort_t pwid[4][SEQL];
    __shared__ float    feat[4 * NF];

    const int b   = blockIdx.x;
    const int tid = threadIdx.x;
    const half_t* hwin16 = (const half_t*)(ws + HWIN_OFF);

#pragma unroll
    for (int i = tid; i < SEQL / 4; i += 256)
        ((int4*)xs)[i] = ((const int4*)(xidx + b * SEQL))[i];
    __syncthreads();

    const int wave = tid >> 6;
    const int lane = tid & 63;

    constexpr int KS[4]  = {2, 3, 4, 5};
    constexpr int SWB[4] = {0, 25, 150, 775};

    const int ks = KS[wave];
    const int Lp = SEQL + 1 - ks;
    const float* swin = ws + SWB[wave];
    const half_t* tab = hwin16 + SWB[wave] * NF;

    // ---- pass 1: window ids + scores, wave softmax ----
    {
        float sv[8];
        float m = -INFINITY;
#pragma unroll
        for (int it = 0; it < 8; ++it) {
            int l = lane + it * 64;
            int w = 0; float s = -INFINITY;
            if (l < Lp) {
                w = xs[l];
                for (int t = 1; t < ks; ++t) w = w * 5 + xs[l + t];
                s = swin[w];
            }
            pwid[wave][l] = (ushort_t)w;
            sv[it] = s;
            m = fmaxf(m, s);
        }
#pragma unroll
        for (int off = 32; off; off >>= 1) m = fmaxf(m, __shfl_xor(m, off));

        float ssum = 0.0f;
#pragma unroll
        for (int it = 0; it < 8; ++it) {
            sv[it] = __expf(sv[it] - m);   // exp(-inf)=0 for padded slots
            ssum += sv[it];
        }
#pragma unroll
        for (int off = 32; off; off >>= 1) ssum += __shfl_xor(ssum, off);
        const float inv = 1.0f / ssum;
#pragma unroll
        for (int it = 0; it < 8; ++it)
            pwS[wave][lane + it * 64] = sv[it] * inv;
    }
    __syncthreads();

    // ---- pass 2: coalesced weighted pool with 8-deep explicit pipeline ----
    // lane = pg*4 + quad : 4 consecutive lanes read the 4 half8s of ONE 64 B row.
    // rbuf[8] keeps ~8 scattered row-loads in flight (VGPR<=64 keeps 32 waves/CU).
    const int quad = lane & 3;
    const int pg   = lane >> 2;

    float a[8];
#pragma unroll
    for (int j = 0; j < 8; ++j) a[j] = 0.0f;

    float pbuf[8];
    half8 rbuf[8];
#pragma unroll
    for (int k = 0; k < 8; ++k) {
        const int pos = k * 16 + pg;
        pbuf[k] = pwS[wave][pos];
        const int off = ((int)pwid[wave][pos]) << 6;
        rbuf[k] = *(const half8*)((const char*)tab + off + quad * 16);
    }

#pragma unroll
    for (int it = 0; it < 32; ++it) {
        const int slot = it & 7;            // compile-time after full unroll
        const float p = pbuf[slot];
        const half8 r = rbuf[slot];
        if (it < 24) {
            const int pos = (it + 8) * 16 + pg;
            pbuf[slot] = pwS[wave][pos];
            const int off = ((int)pwid[wave][pos]) << 6;
            rbuf[slot] = *(const half8*)((const char*)tab + off + quad * 16);
        }
#pragma unroll
        for (int j = 0; j < 8; ++j)
            a[j] += p * (float)r[j];
    }

#pragma unroll
    for (int off = 4; off < 64; off <<= 1) {
#pragma unroll
        for (int j = 0; j < 8; ++j) a[j] += __shfl_xor(a[j], off);
    }
    if (lane < 4) {
        float* fp = feat + wave * NF + lane * 8;
#pragma unroll
        for (int j = 0; j < 8; ++j) fp[j] = a[j];
    }
    __syncthreads();

    // ---- projection + GELU + LayerNorm (wave 0) ----
    if (tid < DOUT) {
        float z = projb[tid];
        const float4* pwr = (const float4*)(projw + tid * (4 * NF));
#pragma unroll
        for (int q = 0; q < 32; ++q) {
            float4 wq = pwr[q];
            const float* fj = feat + q * 4;
            z += wq.x * fj[0] + wq.y * fj[1] + wq.z * fj[2] + wq.w * fj[3];
        }
        z = gelu_exact(z);

        float s1 = z, s2 = z * z;
#pragma unroll
        for (int off = 32; off; off >>= 1) {
            s1 += __shfl_xor(s1, off);
            s2 += __shfl_xor(s2, off);
        }
        const float mu  = s1 * (1.0f / 64.0f);
        const float var = s2 * (1.0f / 64.0f) - mu * mu;
        const float r   = rsqrtf(var + 1e-5f);
        out[b * DOUT + tid] = (z - mu) * r * gamma[tid] + beta[tid];
    }
}

extern "C" void kernel_launch(void* const* d_in, const int* in_sizes, int n_in,
                              void* d_out, int out_size, void* d_ws, size_t ws_size,
                              hipStream_t stream) {
    const int*   xidx = (const int*)d_in[0];
    const float* emb  = (const float*)d_in[1];
    const float* cw[4]; const float* cb[4]; const float* aw[4]; const float* ab[4];
    for (int i = 0; i < 4; ++i) {
        cw[i] = (const float*)d_in[2 + 4 * i];
        cb[i] = (const float*)d_in[3 + 4 * i];
        aw[i] = (const float*)d_in[4 + 4 * i];
        ab[i] = (const float*)d_in[5 + 4 * i];
    }
    const float* projw = (const float*)d_in[18];
    const float* projb = (const float*)d_in[19];
    const float* gm    = (const float*)d_in[20];
    const float* bt    = (const float*)d_in[21];
    float* ws  = (float*)d_ws;
    float* out = (float*)d_out;

    hipLaunchKernelGGL(precompute_taps, dim3((14 * 5 * NF + 255) / 256), dim3(256), 0, stream,
                       emb, cw[0], cw[1], cw[2], cw[3], ws);

    hipLaunchKernelGGL(precompute_windows, dim3((NWIN_TOTAL * NF + 255) / 256), dim3(256), 0, stream,
                       cb[0], aw[0], ab[0],
                       cb[1], aw[1], ab[1],
                       cb[2], aw[2], ab[2],
                       cb[3], aw[3], ab[3],
                       ws);

    hipLaunchKernelGGL(fused_main, dim3(BATCH), dim3(256), 0, stream,
                       xidx, ws, projw, projb, gm, bt, out);
}